// Round 1
// baseline (12534.563 us; speedup 1.0000x reference)
//
#include <hip/hip_runtime.h>
#include <hip/hip_bf16.h>

#define B    64
#define HID  1024
#define EMB  512
#define SEQ  256
#define VOCAB 128
#define G4   4096   // 4*HID

typedef short bf16x8_t __attribute__((ext_vector_type(8)));
typedef float f32x4_t  __attribute__((ext_vector_type(4)));
using bf16 = __hip_bfloat16;

// ---------------- weight / input casts ----------------
__global__ void cast_f32_bf16(const float* __restrict__ src, bf16* __restrict__ dst, int n) {
    int i = blockIdx.x * blockDim.x + threadIdx.x;
    int stride = gridDim.x * blockDim.x;
    for (; i < n; i += stride) dst[i] = __float2bfloat16(src[i]);
}

__global__ void init_hc(const float* __restrict__ h0, const float* __restrict__ c0,
                        bf16* __restrict__ h_init0, bf16* __restrict__ hb1a,
                        float* __restrict__ cb0, float* __restrict__ cb1,
                        float* __restrict__ hm0, float* __restrict__ hm1) {
    int i = blockIdx.x * blockDim.x + threadIdx.x;
    int stride = gridDim.x * blockDim.x;
    for (; i < B * HID; i += stride) {
        float h0v = h0[i];
        float h1v = h0[B * HID + i];
        h_init0[i] = __float2bfloat16(h0v);
        hb1a[i]    = __float2bfloat16(h1v);
        hm0[i] = h0v;  hm1[i] = h1v;
        cb0[i] = c0[i];
        cb1[i] = c0[B * HID + i];
    }
}

// ---------------- fused LSTM step ----------------
// One launch per (t, layer). Grid: 128 WGs, each owns 8 H-cols (32 gate cols:
// i/f/g/o sections for those H-cols). 4 waves: wave&1 -> col tile (16 cols),
// wave>>1 -> row half (32 rows = 2 MFMA row tiles).
// Gates accumulated in fp32 via mfma_f32_16x16x32_bf16, staged to LDS,
// activations + c/h update fused at the end.
template<int KX>
__global__ __launch_bounds__(256) void lstm_step(
    const bf16* __restrict__ xpart,   // layer0: emb_bf [VOCAB][EMB]; layer1: ys0 + t*B*HID
    const int*  __restrict__ xidx,    // layer0: x + t*B ; layer1: nullptr
    const bf16* __restrict__ Wih,     // [G4][KX]
    const bf16* __restrict__ Whh,     // [G4][HID]
    const float* __restrict__ bias,   // [G4]
    const bf16* __restrict__ h_in,    // [B][HID]
    float* __restrict__ cbuf,         // [B][HID] in/out
    bf16*  __restrict__ h_out_bf,     // [B][HID]
    float* __restrict__ h_out_f32)    // [B][HID]
{
    __shared__ float gbuf[64][33];

    const int tid   = threadIdx.x;
    const int l     = tid & 63;
    const int wave  = tid >> 6;
    const int hbase = blockIdx.x * 8;

    const int cl   = ((wave & 1) << 4) + (l & 15);  // 0..31 within WG
    const int sec  = cl >> 3;                        // gate section 0..3
    const int hoff = cl & 7;
    const int gcol = sec * HID + hbase + hoff;       // row of weight matrices

    const int rowbase = (wave >> 1) << 5;            // 0 or 32
    const int m0 = rowbase + (l & 15);
    const int m1 = m0 + 16;
    const int k8 = (l >> 4) << 3;                    // k-chunk offset for this lane

    f32x4_t acc0 = {0.f, 0.f, 0.f, 0.f};
    f32x4_t acc1 = {0.f, 0.f, 0.f, 0.f};

    // ---- phase 1: x-part (K = KX) ----
    const bf16* A0;
    const bf16* A1;
    if (xidx != nullptr) {           // embedding gather (layer 0)
        A0 = xpart + (size_t)xidx[m0] * EMB;
        A1 = xpart + (size_t)xidx[m1] * EMB;
    } else {                         // ys0 rows (layer 1)
        A0 = xpart + (size_t)m0 * KX;
        A1 = xpart + (size_t)m1 * KX;
    }
    const bf16* Bp = Wih + (size_t)gcol * KX;
    #pragma unroll 4
    for (int k = 0; k < KX; k += 32) {
        bf16x8_t a0 = *reinterpret_cast<const bf16x8_t*>(A0 + k + k8);
        bf16x8_t a1 = *reinterpret_cast<const bf16x8_t*>(A1 + k + k8);
        bf16x8_t b  = *reinterpret_cast<const bf16x8_t*>(Bp + k + k8);
        acc0 = __builtin_amdgcn_mfma_f32_16x16x32_bf16(a0, b, acc0, 0, 0, 0);
        acc1 = __builtin_amdgcn_mfma_f32_16x16x32_bf16(a1, b, acc1, 0, 0, 0);
    }

    // ---- phase 2: h-part (K = HID) ----
    const bf16* H0 = h_in + (size_t)m0 * HID;
    const bf16* H1 = h_in + (size_t)m1 * HID;
    const bf16* Bh = Whh + (size_t)gcol * HID;
    #pragma unroll 4
    for (int k = 0; k < HID; k += 32) {
        bf16x8_t a0 = *reinterpret_cast<const bf16x8_t*>(H0 + k + k8);
        bf16x8_t a1 = *reinterpret_cast<const bf16x8_t*>(H1 + k + k8);
        bf16x8_t b  = *reinterpret_cast<const bf16x8_t*>(Bh + k + k8);
        acc0 = __builtin_amdgcn_mfma_f32_16x16x32_bf16(a0, b, acc0, 0, 0, 0);
        acc1 = __builtin_amdgcn_mfma_f32_16x16x32_bf16(a1, b, acc1, 0, 0, 0);
    }

    // ---- stage gates to LDS (C layout: col = lane&15, row = 4*(lane>>4)+reg) ----
    {
        const int r0 = rowbase + ((l >> 4) << 2);
        #pragma unroll
        for (int r = 0; r < 4; ++r) {
            gbuf[r0 + r][cl]      = acc0[r];
            gbuf[r0 + 16 + r][cl] = acc1[r];
        }
    }
    __syncthreads();

    // ---- activations + state update: 512 (m, hh) pairs, 2 per thread ----
    #pragma unroll
    for (int p = tid; p < 512; p += 256) {
        const int m  = p >> 3;
        const int hh = p & 7;
        const int col = hbase + hh;
        float gi = gbuf[m][hh]      + bias[col];
        float gf = gbuf[m][8  + hh] + bias[HID     + col];
        float gg = gbuf[m][16 + hh] + bias[2 * HID + col];
        float go = gbuf[m][24 + hh] + bias[3 * HID + col];

        float si = 1.f / (1.f + expf(-gi));
        float sf = 1.f / (1.f + expf(-gf));
        float so = 1.f / (1.f + expf(-go));
        float tg = tanhf(gg);

        const int idx = m * HID + col;
        float cn = sf * cbuf[idx] + si * tg;
        float hn = so * tanhf(cn);
        cbuf[idx]      = cn;
        h_out_bf[idx]  = __float2bfloat16(hn);
        h_out_f32[idx] = hn;
    }
}

// ---------------- final FC head ----------------
__global__ void logits_kernel(const float* __restrict__ h, const float* __restrict__ Wfc,
                              const float* __restrict__ bfc, float* __restrict__ out) {
    int t = blockIdx.x * blockDim.x + threadIdx.x;
    if (t >= B * VOCAB) return;
    int m = t >> 7, v = t & 127;
    const float4* hp = reinterpret_cast<const float4*>(h + (size_t)m * HID);
    const float4* wp = reinterpret_cast<const float4*>(Wfc + (size_t)v * HID);
    float acc = 0.f;
    #pragma unroll 4
    for (int k = 0; k < HID / 4; ++k) {
        float4 a = hp[k], w = wp[k];
        acc += a.x * w.x + a.y * w.y + a.z * w.z + a.w * w.w;
    }
    out[t] = acc + bfc[v];
}

__global__ void copy_out(const float* __restrict__ hm0, const float* __restrict__ hm1,
                         const float* __restrict__ cb0, const float* __restrict__ cb1,
                         float* __restrict__ out) {
    const int n = B * HID;
    int i = blockIdx.x * blockDim.x + threadIdx.x;
    int stride = gridDim.x * blockDim.x;
    for (; i < n; i += stride) {
        out[B * VOCAB + i]         = hm0[i];
        out[B * VOCAB + n + i]     = hm1[i];
        out[B * VOCAB + 2 * n + i] = cb0[i];
        out[B * VOCAB + 3 * n + i] = cb1[i];
    }
}

// ---------------- launch ----------------
extern "C" void kernel_launch(void* const* d_in, const int* in_sizes, int n_in,
                              void* d_out, int out_size, void* d_ws, size_t ws_size,
                              hipStream_t stream) {
    const int*   x    = (const int*)d_in[0];
    const float* h0   = (const float*)d_in[1];
    const float* c0   = (const float*)d_in[2];
    const float* emb  = (const float*)d_in[3];
    const float* Wih0 = (const float*)d_in[4];
    const float* Whh0 = (const float*)d_in[5];
    const float* b0   = (const float*)d_in[6];
    const float* Wih1 = (const float*)d_in[7];
    const float* Whh1 = (const float*)d_in[8];
    const float* b1   = (const float*)d_in[9];
    const float* Wfc  = (const float*)d_in[10];
    const float* bfc  = (const float*)d_in[11];
    float* out = (float*)d_out;

    char* ws = (char*)d_ws;
    size_t off = 0;
    auto alloc = [&](size_t bytes) -> void* {
        void* p = ws + off;
        off += (bytes + 255) & ~(size_t)255;
        return p;
    };
    bf16* emb_bf  = (bf16*)alloc((size_t)VOCAB * EMB * 2);
    bf16* Wih0_bf = (bf16*)alloc((size_t)G4 * EMB * 2);
    bf16* Whh0_bf = (bf16*)alloc((size_t)G4 * HID * 2);
    bf16* Wih1_bf = (bf16*)alloc((size_t)G4 * HID * 2);
    bf16* Whh1_bf = (bf16*)alloc((size_t)G4 * HID * 2);
    bf16* ys0     = (bf16*)alloc((size_t)SEQ * B * HID * 2);
    bf16* h_init0 = (bf16*)alloc((size_t)B * HID * 2);
    bf16* hb1a    = (bf16*)alloc((size_t)B * HID * 2);
    bf16* hb1b    = (bf16*)alloc((size_t)B * HID * 2);
    float* cb0    = (float*)alloc((size_t)B * HID * 4);
    float* cb1    = (float*)alloc((size_t)B * HID * 4);
    float* hm0    = (float*)alloc((size_t)B * HID * 4);
    float* hm1    = (float*)alloc((size_t)B * HID * 4);
    (void)ws_size; (void)in_sizes; (void)n_in; (void)out_size;

    cast_f32_bf16<<<64,  256, 0, stream>>>(emb,  emb_bf,  VOCAB * EMB);
    cast_f32_bf16<<<512, 256, 0, stream>>>(Wih0, Wih0_bf, G4 * EMB);
    cast_f32_bf16<<<512, 256, 0, stream>>>(Whh0, Whh0_bf, G4 * HID);
    cast_f32_bf16<<<512, 256, 0, stream>>>(Wih1, Wih1_bf, G4 * HID);
    cast_f32_bf16<<<512, 256, 0, stream>>>(Whh1, Whh1_bf, G4 * HID);
    init_hc<<<64, 256, 0, stream>>>(h0, c0, h_init0, hb1a, cb0, cb1, hm0, hm1);

    // layer 0: h ping-pongs through ys0 rows themselves
    for (int t = 0; t < SEQ; ++t) {
        const bf16* hin = (t == 0) ? h_init0 : ys0 + (size_t)(t - 1) * B * HID;
        lstm_step<EMB><<<128, 256, 0, stream>>>(
            emb_bf, x + t * B, Wih0_bf, Whh0_bf, b0,
            hin, cb0, ys0 + (size_t)t * B * HID, hm0);
    }
    // layer 1
    for (int t = 0; t < SEQ; ++t) {
        const bf16* hin = (t & 1) ? hb1b : hb1a;
        bf16* hout      = (t & 1) ? hb1a : hb1b;
        lstm_step<HID><<<128, 256, 0, stream>>>(
            ys0 + (size_t)t * B * HID, nullptr, Wih1_bf, Whh1_bf, b1,
            hin, cb1, hout, hm1);
    }

    logits_kernel<<<(B * VOCAB + 255) / 256, 256, 0, stream>>>(hm1, Wfc, bfc, out);
    copy_out<<<256, 256, 0, stream>>>(hm0, hm1, cb0, cb1, out);
}